// Round 3
// baseline (7046.263 us; speedup 1.0000x reference)
//
#include <hip/hip_runtime.h>
#include <hip/hip_bf16.h>
#include <cstdint>

#define DDAYS 5
#define TT 8192
#define FF 768
#define HH 64
#define GG 256  // 4*H

__device__ __forceinline__ float fast_tanh(float x) {
    return 1.f - 2.f / (__expf(2.f * x) + 1.f);
}
__device__ __forceinline__ float fast_sig(float x) {
    return 1.f / (1.f + __expf(-x));
}

// ---------------------------------------------------------------------------
// Kernel 1: ux[m][g] = sum_f A[m][f] * B[g][f]   (bias added later in scan)
// ---------------------------------------------------------------------------
__global__ __launch_bounds__(256, 2) void gemm_ux(
    const float* __restrict__ A, const float* __restrict__ B,
    float* __restrict__ C)
{
    __shared__ __align__(16) float As[16][132];
    __shared__ __align__(16) float Bs[16][132];
    const int tid = threadIdx.x;
    const int m0 = blockIdx.x * 128;
    const int n0 = blockIdx.y * 128;
    const int tx = tid & 15, ty = tid >> 4;
    const int i0 = tx * 8, j0 = ty * 8;
    const int lrow = tid >> 2, lc4 = tid & 3;

    const float* Ap = A + (size_t)(m0 + lrow) * FF + lc4 * 4;
    const float* Bp = B + (size_t)(n0 + lrow) * FF + lc4 * 4;

    float4 pa0 = *(const float4*)(Ap);
    float4 pa1 = *(const float4*)(Ap + 64 * FF);
    float4 pb0 = *(const float4*)(Bp);
    float4 pb1 = *(const float4*)(Bp + 64 * FF);

    float acc[8][8] = {};

    for (int kt = 0; kt < FF / 16; ++kt) {
        __syncthreads();
        {
            const int kk = lc4 * 4;
            As[kk + 0][lrow] = pa0.x; As[kk + 1][lrow] = pa0.y;
            As[kk + 2][lrow] = pa0.z; As[kk + 3][lrow] = pa0.w;
            As[kk + 0][lrow + 64] = pa1.x; As[kk + 1][lrow + 64] = pa1.y;
            As[kk + 2][lrow + 64] = pa1.z; As[kk + 3][lrow + 64] = pa1.w;
            Bs[kk + 0][lrow] = pb0.x; Bs[kk + 1][lrow] = pb0.y;
            Bs[kk + 2][lrow] = pb0.z; Bs[kk + 3][lrow] = pb0.w;
            Bs[kk + 0][lrow + 64] = pb1.x; Bs[kk + 1][lrow + 64] = pb1.y;
            Bs[kk + 2][lrow + 64] = pb1.z; Bs[kk + 3][lrow + 64] = pb1.w;
        }
        __syncthreads();
        if (kt + 1 < FF / 16) {
            const int k0 = (kt + 1) * 16;
            pa0 = *(const float4*)(Ap + k0);
            pa1 = *(const float4*)(Ap + 64 * FF + k0);
            pb0 = *(const float4*)(Bp + k0);
            pb1 = *(const float4*)(Bp + 64 * FF + k0);
        }
#pragma unroll
        for (int k = 0; k < 16; ++k) {
            float a[8], b[8];
            *(float4*)&a[0] = *(const float4*)&As[k][i0];
            *(float4*)&a[4] = *(const float4*)&As[k][i0 + 4];
            *(float4*)&b[0] = *(const float4*)&Bs[k][j0];
            *(float4*)&b[4] = *(const float4*)&Bs[k][j0 + 4];
#pragma unroll
            for (int r = 0; r < 8; ++r)
#pragma unroll
                for (int c = 0; c < 8; ++c)
                    acc[r][c] = fmaf(a[r], b[c], acc[r][c]);
        }
    }
#pragma unroll
    for (int r = 0; r < 8; ++r) {
        float4 s0 = make_float4(acc[r][0], acc[r][1], acc[r][2], acc[r][3]);
        float4 s1 = make_float4(acc[r][4], acc[r][5], acc[r][6], acc[r][7]);
        float* Cp = C + (size_t)(m0 + i0 + r) * GG + n0 + j0;
        *(float4*)Cp = s0;
        *(float4*)(Cp + 4) = s1;
    }
}

// ---------------------------------------------------------------------------
// Kernel 2: TimeLSTM scan. One block (4 waves) per day.
// Wave wv owns columns jj in [16wv, 16wv+16); lane = gt*16 + jl handles
// gate gt of column jj = 16wv+jl. All 4 gates of a column live in the SAME
// wave -> gate exchange via 4 __shfl, no LDS round-trip. Cross-wave state
// (h,c: 64 floats each) is double-buffered in LDS -> ONE barrier per step.
// Weights pinned in registers (launch_bounds(256,1): no VGPR cap).
// u, t prefetched 4 steps ahead in rolling registers (unroll-4).
// ---------------------------------------------------------------------------
__global__ __launch_bounds__(256, 1) void scan_kernel(
    const float* __restrict__ ux, const float* __restrict__ ts,
    const float* __restrict__ Ww, const float* __restrict__ Wb,
    const float* __restrict__ Ub,
    const float* __restrict__ Dw, const float* __restrict__ Db,
    float* __restrict__ y, float* __restrict__ hfin)
{
    const int d = blockIdx.x;
    const int tid = threadIdx.x;
    const int wv = tid >> 6;
    const int lane = tid & 63;
    const int gt = lane >> 4;        // 0=f 1=i 2=o 3=g
    const int jl = lane & 15;
    const int jj = (wv << 4) | jl;   // column 0..63
    const int row = (gt << 6) | jj;  // W_all row (gate-major)

    // W_all row in registers
    float wall[64];
#pragma unroll
    for (int k = 0; k < 16; k++) {
        float4 v = *(const float4*)&Ww[row * 64 + 4 * k];
        wall[4 * k] = v.x; wall[4 * k + 1] = v.y;
        wall[4 * k + 2] = v.z; wall[4 * k + 3] = v.w;
    }
    const float bias = Wb[row] + Ub[row];

    // quarter of W_d row jj (this lane covers k in [16gt,16gt+16))
    float wd16[16];
#pragma unroll
    for (int k = 0; k < 4; k++) {
        float4 v = *(const float4*)&Dw[jj * 64 + gt * 16 + 4 * k];
        wd16[4 * k] = v.x; wd16[4 * k + 1] = v.y;
        wd16[4 * k + 2] = v.z; wd16[4 * k + 3] = v.w;
    }
    const float wdb = Db[jj];

    __shared__ __align__(16) float h_all[2][64];
    __shared__ __align__(16) float c_all[2][64];
    if (tid < 64) { h_all[0][tid] = 0.f; c_all[0][tid] = 0.f; }
    __syncthreads();

    const float* uxd = ux + (size_t)d * TT * GG + row;
    const float* tsd = ts + (size_t)d * TT;
    float* yd = y + (size_t)d * TT * HH;

    float up[4], tp[4];
#pragma unroll
    for (int i = 0; i < 4; i++) {
        up[i] = uxd[(size_t)i * GG];
        tp[i] = tsd[i];
    }

    for (int t = 0; t < TT; t += 4) {
#pragma unroll
        for (int i = 0; i < 4; ++i) {
            const int tc = t + i;
            const int rb = tc & 1, nb = rb ^ 1;
            const float ucur = up[i], tcur = tp[i];
            // issue prefetch for step tc+4 (4 steps of slack)
            {
                int tn = tc + 4; if (tn > TT - 1) tn = TT - 1;
                up[i] = uxd[(size_t)tn * GG];
                tp[i] = tsd[tn];
            }

            // dot64(h, W_all[row]) — LDS broadcast reads, 4 acc chains
            float a0 = 0.f, a1 = 0.f, a2 = 0.f, a3 = 0.f;
#pragma unroll
            for (int k = 0; k < 64; k += 4) {
                float4 h4 = *(const float4*)&h_all[rb][k];
                a0 = fmaf(h4.x, wall[k], a0);
                a1 = fmaf(h4.y, wall[k + 1], a1);
                a2 = fmaf(h4.z, wall[k + 2], a2);
                a3 = fmaf(h4.w, wall[k + 3], a3);
            }
            // quarter dot for c_s1 of column jj
            float p0 = 0.f, p1 = 0.f;
#pragma unroll
            for (int k = 0; k < 16; k += 4) {
                float4 c4 = *(const float4*)&c_all[rb][(gt << 4) + k];
                p0 = fmaf(c4.x, wd16[k], p0);
                p1 = fmaf(c4.y, wd16[k + 1], p1);
                p0 = fmaf(c4.z, wd16[k + 2], p0);
                p1 = fmaf(c4.w, wd16[k + 3], p1);
            }
            float p = p0 + p1;
            p += __shfl_xor(p, 16);
            p += __shfl_xor(p, 32);
            const float cs1 = fast_tanh(p + wdb);

            const float pre = (a0 + a1) + (a2 + a3) + bias + ucur;
            const float gv = (gt == 3) ? fast_tanh(pre) : fast_sig(pre);

            const float c_old = c_all[rb][jj];

            // gather the 4 gates of column jj (all in this wave)
            const float fg = __shfl(gv, jl);
            const float ig = __shfl(gv, jl + 16);
            const float og = __shfl(gv, jl + 32);
            const float gg = __shfl(gv, jl + 48);

            const float cadj = c_old + cs1 * (tcur - 1.f);
            const float cn = fmaf(fg, cadj, ig * gg);
            const float hn = og * fast_tanh(cn);

            if (gt == 2) yd[(size_t)tc * HH + jj] = fast_tanh(gv);
            if (gt == 0) { h_all[nb][jj] = hn; c_all[nb][jj] = cn; }
            __syncthreads();
        }
    }
    // TT even: final state (after step TT-1, which wrote nb = 0)
    if (tid < 64) hfin[d * 64 + tid] = h_all[0][tid];
}

// ---------------------------------------------------------------------------
// Kernel 3: score[d][t] = V . tanh(q_d + W2 y_dt + b2) + Vb
// ---------------------------------------------------------------------------
#define TW 32
__global__ __launch_bounds__(256) void score_kernel(
    const float* __restrict__ y, const float* __restrict__ hfin,
    const float* __restrict__ W1, const float* __restrict__ b1,
    const float* __restrict__ W2, const float* __restrict__ b2,
    const float* __restrict__ Vw, const float* __restrict__ Vb,
    float* __restrict__ score)
{
    const int d = blockIdx.y;
    const int tid = threadIdx.x;
    const int lane = tid & 63, wv = tid >> 6;
    __shared__ __align__(16) float hf[64];
    __shared__ float qs[64];
    if (tid < 64) hf[tid] = hfin[d * 64 + tid];
    __syncthreads();
    if (tid < 64) {
        float acc = b1[tid];
#pragma unroll
        for (int k = 0; k < 16; k++) {
            float4 w = *(const float4*)&W1[tid * 64 + 4 * k];
            float4 h4 = *(const float4*)&hf[4 * k];
            acc += w.x * h4.x + w.y * h4.y + w.z * h4.z + w.w * h4.w;
        }
        qs[tid] = acc;
    }
    __syncthreads();

    float w2[64];
#pragma unroll
    for (int k = 0; k < 16; k++) {
        float4 v = *(const float4*)&W2[lane * 64 + 4 * k];
        w2[4 * k] = v.x; w2[4 * k + 1] = v.y;
        w2[4 * k + 2] = v.z; w2[4 * k + 3] = v.w;
    }
    const float qb = qs[lane] + b2[lane];
    const float vr = Vw[lane];
    const float vb = Vb[0];
    const int tbase = blockIdx.x * (4 * TW) + wv * TW;
    const float* yd = y + (size_t)d * TT * HH;

    for (int i = 0; i < TW; i++) {
        const int t = tbase + i;
        const float* yrow = yd + (size_t)t * HH;
        float a0 = 0.f, a1 = 0.f, a2 = 0.f, a3 = 0.f;
#pragma unroll
        for (int k = 0; k < 64; k += 4) {
            float4 yv = *(const float4*)&yrow[k];
            a0 = fmaf(yv.x, w2[k], a0);
            a1 = fmaf(yv.y, w2[k + 1], a1);
            a2 = fmaf(yv.z, w2[k + 2], a2);
            a3 = fmaf(yv.w, w2[k + 3], a3);
        }
        float v = fast_tanh(qb + (a0 + a1) + (a2 + a3));
        float s = v * vr;
#pragma unroll
        for (int off = 32; off > 0; off >>= 1) s += __shfl_xor(s, off);
        if (lane == 0) score[(size_t)d * TT + t] = s + vb;
    }
}

// ---------------------------------------------------------------------------
// Kernel 4: per-day softmax over T + ctx[d][j] = sum_t attn * y
// ---------------------------------------------------------------------------
__global__ __launch_bounds__(256) void ctx_kernel(
    const float* __restrict__ score, const float* __restrict__ y,
    float* __restrict__ ctx)
{
    const int d = blockIdx.x;
    const int tid = threadIdx.x;
    __shared__ float red[256];
    const float* sc = score + (size_t)d * TT;

    float m = -1e30f;
    for (int t = tid; t < TT; t += 256) m = fmaxf(m, sc[t]);
    red[tid] = m; __syncthreads();
    for (int s = 128; s > 0; s >>= 1) {
        if (tid < s) red[tid] = fmaxf(red[tid], red[tid + s]);
        __syncthreads();
    }
    m = red[0]; __syncthreads();

    float se = 0.f;
    for (int t = tid; t < TT; t += 256) se += __expf(sc[t] - m);
    red[tid] = se; __syncthreads();
    for (int s = 128; s > 0; s >>= 1) {
        if (tid < s) red[tid] += red[tid + s];
        __syncthreads();
    }
    const float inv = 1.f / red[0];
    __syncthreads();

    const int j = tid & 63, grp = tid >> 6;
    const float* yd = y + (size_t)d * TT * HH;
    float a = 0.f;
    for (int t = grp; t < TT; t += 4)
        a = fmaf(__expf(sc[t] - m), yd[(size_t)t * HH + j], a);
    red[tid] = a; __syncthreads();
    if (tid < 64)
        ctx[d * 64 + tid] =
            (red[tid] + red[tid + 64] + red[tid + 128] + red[tid + 192]) * inv;
}

// ---------------------------------------------------------------------------
// Kernel 5: day LSTM (1 step) + day attention + stock head -> out[1]
// ---------------------------------------------------------------------------
__global__ __launch_bounds__(320) void final_kernel(
    const float* __restrict__ ctx,
    const float* __restrict__ Wih, const float* __restrict__ bih,
    const float* __restrict__ bhh,
    const float* __restrict__ W1, const float* __restrict__ b1,
    const float* __restrict__ W2, const float* __restrict__ b2,
    const float* __restrict__ Vw, const float* __restrict__ Vb,
    const float* __restrict__ stw, const float* __restrict__ stb,
    float* __restrict__ out)
{
    const int tid = threadIdx.x;
    const int dd = tid >> 6, j = tid & 63;
    __shared__ __align__(16) float ctxs[320];
    __shared__ float gsh[5 * 256];
    __shared__ __align__(16) float fulls[320];
    __shared__ __align__(16) float lasts[320];
    __shared__ float s2[5];

    ctxs[tid] = ctx[tid];
    __syncthreads();

    if (tid < 256) {
        float w[64];
#pragma unroll
        for (int k = 0; k < 16; k++) {
            float4 v = *(const float4*)&Wih[tid * 64 + 4 * k];
            w[4 * k] = v.x; w[4 * k + 1] = v.y;
            w[4 * k + 2] = v.z; w[4 * k + 3] = v.w;
        }
        const float bb = bih[tid] + bhh[tid];
        for (int dday = 0; dday < 5; ++dday) {
            float acc = bb;
#pragma unroll
            for (int k = 0; k < 64; k += 4) {
                float4 c4 = *(const float4*)&ctxs[dday * 64 + k];
                acc += w[k] * c4.x + w[k + 1] * c4.y + w[k + 2] * c4.z +
                       w[k + 3] * c4.w;
            }
            gsh[dday * 256 + tid] = acc;
        }
    }
    __syncthreads();
    {
        float gi = gsh[dd * 256 + j];
        float gg2 = gsh[dd * 256 + 128 + j];
        float go = gsh[dd * 256 + 192 + j];
        float c = fast_sig(gi) * fast_tanh(gg2);
        float hd = fast_sig(go) * fast_tanh(c);
        lasts[tid] = hd;
        fulls[tid] = fast_tanh(hd);
    }
    __syncthreads();
    {
        float w1r[64], w2r[64];
#pragma unroll
        for (int k = 0; k < 16; k++) {
            float4 v1 = *(const float4*)&W1[j * 64 + 4 * k];
            float4 v2 = *(const float4*)&W2[j * 64 + 4 * k];
            w1r[4 * k] = v1.x; w1r[4 * k + 1] = v1.y;
            w1r[4 * k + 2] = v1.z; w1r[4 * k + 3] = v1.w;
            w2r[4 * k] = v2.x; w2r[4 * k + 1] = v2.y;
            w2r[4 * k + 2] = v2.z; w2r[4 * k + 3] = v2.w;
        }
        float acc = b1[j] + b2[j];
#pragma unroll
        for (int k = 0; k < 64; ++k)
            acc += w1r[k] * lasts[dd * 64 + k] + w2r[k] * fulls[dd * 64 + k];
        float v = fast_tanh(acc) * Vw[j];
#pragma unroll
        for (int off = 32; off > 0; off >>= 1) v += __shfl_xor(v, off);
        if (j == 0) s2[dd] = v + Vb[0];
    }
    __syncthreads();
    if (tid < 64) {
        float m = s2[0];
#pragma unroll
        for (int dday = 1; dday < 5; ++dday) m = fmaxf(m, s2[dday]);
        float se = 0.f, ft = 0.f;
#pragma unroll
        for (int dday = 0; dday < 5; ++dday) {
            float e = __expf(s2[dday] - m);
            se += e;
            ft += e * fulls[dday * 64 + tid];
        }
        ft /= se;
        float pv = ft * stw[tid];
#pragma unroll
        for (int off = 32; off > 0; off >>= 1) pv += __shfl_xor(pv, off);
        if (tid == 0) out[0] = 3.f * fast_tanh(pv + stb[0]);
    }
}

// ---------------------------------------------------------------------------
extern "C" void kernel_launch(void* const* d_in, const int* in_sizes, int n_in,
                              void* d_out, int out_size, void* d_ws,
                              size_t ws_size, hipStream_t stream)
{
    const float* x     = (const float*)d_in[0];
    const float* ts    = (const float*)d_in[1];
    const float* Wallw = (const float*)d_in[3];
    const float* Wallb = (const float*)d_in[4];
    const float* Uallw = (const float*)d_in[5];
    const float* Uallb = (const float*)d_in[6];
    const float* Wdw   = (const float*)d_in[7];
    const float* Wdb   = (const float*)d_in[8];
    const float* taW1w = (const float*)d_in[9];
    const float* taW1b = (const float*)d_in[10];
    const float* taW2w = (const float*)d_in[11];
    const float* taW2b = (const float*)d_in[12];
    const float* taVw  = (const float*)d_in[13];
    const float* taVb  = (const float*)d_in[14];
    const float* Wih   = (const float*)d_in[15];
    const float* bih   = (const float*)d_in[17];
    const float* bhh   = (const float*)d_in[18];
    const float* daW1w = (const float*)d_in[19];
    const float* daW1b = (const float*)d_in[20];
    const float* daW2w = (const float*)d_in[21];
    const float* daW2b = (const float*)d_in[22];
    const float* daVw  = (const float*)d_in[23];
    const float* daVb  = (const float*)d_in[24];
    const float* stw   = (const float*)d_in[25];
    const float* stb   = (const float*)d_in[26];
    float* out = (float*)d_out;

    float* ux = (float*)d_ws;                       // [5][8192][256]
    float* yb = ux + (size_t)DDAYS * TT * GG;       // [5][8192][64]
    float* sc = yb + (size_t)DDAYS * TT * HH;       // [5][8192]
    float* hf = sc + (size_t)DDAYS * TT;            // [5][64]
    float* cx = hf + 512;                           // [5][64]

    gemm_ux<<<dim3(320, 2), 256, 0, stream>>>(x, Uallw, ux);
    scan_kernel<<<dim3(DDAYS), 256, 0, stream>>>(ux, ts, Wallw, Wallb, Uallb,
                                                 Wdw, Wdb, yb, hf);
    score_kernel<<<dim3(TT / (4 * TW), DDAYS), 256, 0, stream>>>(
        yb, hf, taW1w, taW1b, taW2w, taW2b, taVw, taVb, sc);
    ctx_kernel<<<dim3(DDAYS), 256, 0, stream>>>(sc, yb, cx);
    final_kernel<<<dim3(1), 320, 0, stream>>>(cx, Wih, bih, bhh, daW1w, daW1b,
                                              daW2w, daW2b, daVw, daVb, stw,
                                              stb, out);
}

// Round 4
// 6823.693 us; speedup vs baseline: 1.0326x; 1.0326x over previous
//
#include <hip/hip_runtime.h>
#include <hip/hip_bf16.h>
#include <cstdint>

#define DDAYS 5
#define TT 8192
#define FF 768
#define HH 64
#define GG 256  // 4*H

__device__ __forceinline__ float fast_tanh(float x) {
    return 1.f - 2.f / (__expf(2.f * x) + 1.f);
}
__device__ __forceinline__ float fast_sig(float x) {
    return 1.f / (1.f + __expf(-x));
}

// ---------------------------------------------------------------------------
// Kernel 1: ux[m][g] = sum_f A[m][f] * B[g][f]   (bias added later in scan)
// ---------------------------------------------------------------------------
__global__ __launch_bounds__(256, 2) void gemm_ux(
    const float* __restrict__ A, const float* __restrict__ B,
    float* __restrict__ C)
{
    __shared__ __align__(16) float As[16][132];
    __shared__ __align__(16) float Bs[16][132];
    const int tid = threadIdx.x;
    const int m0 = blockIdx.x * 128;
    const int n0 = blockIdx.y * 128;
    const int tx = tid & 15, ty = tid >> 4;
    const int i0 = tx * 8, j0 = ty * 8;
    const int lrow = tid >> 2, lc4 = tid & 3;

    const float* Ap = A + (size_t)(m0 + lrow) * FF + lc4 * 4;
    const float* Bp = B + (size_t)(n0 + lrow) * FF + lc4 * 4;

    float4 pa0 = *(const float4*)(Ap);
    float4 pa1 = *(const float4*)(Ap + 64 * FF);
    float4 pb0 = *(const float4*)(Bp);
    float4 pb1 = *(const float4*)(Bp + 64 * FF);

    float acc[8][8] = {};

    for (int kt = 0; kt < FF / 16; ++kt) {
        __syncthreads();
        {
            const int kk = lc4 * 4;
            As[kk + 0][lrow] = pa0.x; As[kk + 1][lrow] = pa0.y;
            As[kk + 2][lrow] = pa0.z; As[kk + 3][lrow] = pa0.w;
            As[kk + 0][lrow + 64] = pa1.x; As[kk + 1][lrow + 64] = pa1.y;
            As[kk + 2][lrow + 64] = pa1.z; As[kk + 3][lrow + 64] = pa1.w;
            Bs[kk + 0][lrow] = pb0.x; Bs[kk + 1][lrow] = pb0.y;
            Bs[kk + 2][lrow] = pb0.z; Bs[kk + 3][lrow] = pb0.w;
            Bs[kk + 0][lrow + 64] = pb1.x; Bs[kk + 1][lrow + 64] = pb1.y;
            Bs[kk + 2][lrow + 64] = pb1.z; Bs[kk + 3][lrow + 64] = pb1.w;
        }
        __syncthreads();
        if (kt + 1 < FF / 16) {
            const int k0 = (kt + 1) * 16;
            pa0 = *(const float4*)(Ap + k0);
            pa1 = *(const float4*)(Ap + 64 * FF + k0);
            pb0 = *(const float4*)(Bp + k0);
            pb1 = *(const float4*)(Bp + 64 * FF + k0);
        }
#pragma unroll
        for (int k = 0; k < 16; ++k) {
            float a[8], b[8];
            *(float4*)&a[0] = *(const float4*)&As[k][i0];
            *(float4*)&a[4] = *(const float4*)&As[k][i0 + 4];
            *(float4*)&b[0] = *(const float4*)&Bs[k][j0];
            *(float4*)&b[4] = *(const float4*)&Bs[k][j0 + 4];
#pragma unroll
            for (int r = 0; r < 8; ++r)
#pragma unroll
                for (int c = 0; c < 8; ++c)
                    acc[r][c] = fmaf(a[r], b[c], acc[r][c]);
        }
    }
#pragma unroll
    for (int r = 0; r < 8; ++r) {
        float4 s0 = make_float4(acc[r][0], acc[r][1], acc[r][2], acc[r][3]);
        float4 s1 = make_float4(acc[r][4], acc[r][5], acc[r][6], acc[r][7]);
        float* Cp = C + (size_t)(m0 + i0 + r) * GG + n0 + j0;
        *(float4*)Cp = s0;
        *(float4*)(Cp + 4) = s1;
    }
}

// ---------------------------------------------------------------------------
// Kernel 2: TimeLSTM scan. One block (4 waves) per day.
// Wave wv owns columns jj in [16wv,16wv+16); lane = gt*16+jl. Gate exchange
// intra-wave via __shfl. h/c double-buffered in LDS, ONE barrier per step.
// KEY (R3 fix): raw s_barrier + lgkmcnt(0) only — __syncthreads()'s
// vmcnt(0) drain was serializing the u/ts prefetch (L3-latency ~500-900cyc)
// into every step. Counted vmcnt on up[i] use keeps 4 steps of slack.
// ---------------------------------------------------------------------------
__global__ __launch_bounds__(256, 1) void scan_kernel(
    const float* __restrict__ ux, const float* __restrict__ ts,
    const float* __restrict__ Ww, const float* __restrict__ Wb,
    const float* __restrict__ Ub,
    const float* __restrict__ Dw, const float* __restrict__ Db,
    float* __restrict__ y, float* __restrict__ hfin)
{
    const int d = blockIdx.x;
    const int tid = threadIdx.x;
    const int wv = tid >> 6;
    const int lane = tid & 63;
    const int gt = lane >> 4;        // 0=f 1=i 2=o 3=g
    const int jl = lane & 15;
    const int jj = (wv << 4) | jl;   // column 0..63
    const int row = (gt << 6) | jj;  // W_all row (gate-major)

    // W_all row in registers
    float wall[64];
#pragma unroll
    for (int k = 0; k < 16; k++) {
        float4 v = *(const float4*)&Ww[row * 64 + 4 * k];
        wall[4 * k] = v.x; wall[4 * k + 1] = v.y;
        wall[4 * k + 2] = v.z; wall[4 * k + 3] = v.w;
    }
    const float bias = Wb[row] + Ub[row];

    // quarter of W_d row jj (this lane covers k in [16gt,16gt+16))
    float wd16[16];
#pragma unroll
    for (int k = 0; k < 4; k++) {
        float4 v = *(const float4*)&Dw[jj * 64 + gt * 16 + 4 * k];
        wd16[4 * k] = v.x; wd16[4 * k + 1] = v.y;
        wd16[4 * k + 2] = v.z; wd16[4 * k + 3] = v.w;
    }
    const float wdb = Db[jj];

    __shared__ __align__(16) float h_all[2][64];
    __shared__ __align__(16) float c_all[2][64];
    if (tid < 64) { h_all[0][tid] = 0.f; c_all[0][tid] = 0.f; }
    __syncthreads();

    const float* uxd = ux + (size_t)d * TT * GG + row;
    const float* tsd = ts + (size_t)d * TT;
    float* yd = y + (size_t)d * TT * HH;

    float up[4], tp[4];
#pragma unroll
    for (int i = 0; i < 4; i++) {
        up[i] = uxd[(size_t)i * GG];
        tp[i] = tsd[i];
    }

    for (int t = 0; t < TT; t += 4) {
#pragma unroll
        for (int i = 0; i < 4; ++i) {
            const int tc = t + i;
            const int rb = tc & 1, nb = rb ^ 1;
            const float ucur = up[i], tcur = tp[i];
            // issue prefetch for step tc+4 (4 steps of slack)
            {
                int tn = tc + 4; if (tn > TT - 1) tn = TT - 1;
                up[i] = uxd[(size_t)tn * GG];
                tp[i] = tsd[tn];
            }

            // dot64(h, W_all[row]) — LDS broadcast reads, 4 acc chains
            float a0 = 0.f, a1 = 0.f, a2 = 0.f, a3 = 0.f;
#pragma unroll
            for (int k = 0; k < 64; k += 4) {
                float4 h4 = *(const float4*)&h_all[rb][k];
                a0 = fmaf(h4.x, wall[k], a0);
                a1 = fmaf(h4.y, wall[k + 1], a1);
                a2 = fmaf(h4.z, wall[k + 2], a2);
                a3 = fmaf(h4.w, wall[k + 3], a3);
            }
            // quarter dot for c_s1 of column jj
            float p0 = 0.f, p1 = 0.f;
#pragma unroll
            for (int k = 0; k < 16; k += 4) {
                float4 c4 = *(const float4*)&c_all[rb][(gt << 4) + k];
                p0 = fmaf(c4.x, wd16[k], p0);
                p1 = fmaf(c4.y, wd16[k + 1], p1);
                p0 = fmaf(c4.z, wd16[k + 2], p0);
                p1 = fmaf(c4.w, wd16[k + 3], p1);
            }
            float p = p0 + p1;
            p += __shfl_xor(p, 16);
            p += __shfl_xor(p, 32);
            const float cs1 = fast_tanh(p + wdb);

            const float pre = (a0 + a1) + (a2 + a3) + bias + ucur;
            const float gv = (gt == 3) ? fast_tanh(pre) : fast_sig(pre);

            const float c_old = c_all[rb][jj];

            // gather the 4 gates of column jj (all in this wave)
            const float fg = __shfl(gv, jl);
            const float ig = __shfl(gv, jl + 16);
            const float og = __shfl(gv, jl + 32);
            const float gg = __shfl(gv, jl + 48);

            const float cadj = c_old + cs1 * (tcur - 1.f);
            const float cn = fmaf(fg, cadj, ig * gg);
            const float hn = og * fast_tanh(cn);

            if (gt == 2) yd[(size_t)tc * HH + jj] = fast_tanh(gv);
            if (gt == 0) { h_all[nb][jj] = hn; c_all[nb][jj] = cn; }

            // Raw barrier: wait ONLY on LDS (lgkmcnt) so the u/ts global
            // prefetches stay in flight across the barrier (no vmcnt drain).
            asm volatile("s_waitcnt lgkmcnt(0)" ::: "memory");
            __builtin_amdgcn_sched_barrier(0);
            __builtin_amdgcn_s_barrier();
            __builtin_amdgcn_sched_barrier(0);
        }
    }
    // TT even: final state (after step TT-1, which wrote nb = 0)
    if (tid < 64) hfin[d * 64 + tid] = h_all[0][tid];
}

// ---------------------------------------------------------------------------
// Kernel 3: score[d][t] = V . tanh(q_d + W2 y_dt + b2) + Vb
// ---------------------------------------------------------------------------
#define TW 32
__global__ __launch_bounds__(256) void score_kernel(
    const float* __restrict__ y, const float* __restrict__ hfin,
    const float* __restrict__ W1, const float* __restrict__ b1,
    const float* __restrict__ W2, const float* __restrict__ b2,
    const float* __restrict__ Vw, const float* __restrict__ Vb,
    float* __restrict__ score)
{
    const int d = blockIdx.y;
    const int tid = threadIdx.x;
    const int lane = tid & 63, wv = tid >> 6;
    __shared__ __align__(16) float hf[64];
    __shared__ float qs[64];
    if (tid < 64) hf[tid] = hfin[d * 64 + tid];
    __syncthreads();
    if (tid < 64) {
        float acc = b1[tid];
#pragma unroll
        for (int k = 0; k < 16; k++) {
            float4 w = *(const float4*)&W1[tid * 64 + 4 * k];
            float4 h4 = *(const float4*)&hf[4 * k];
            acc += w.x * h4.x + w.y * h4.y + w.z * h4.z + w.w * h4.w;
        }
        qs[tid] = acc;
    }
    __syncthreads();

    float w2[64];
#pragma unroll
    for (int k = 0; k < 16; k++) {
        float4 v = *(const float4*)&W2[lane * 64 + 4 * k];
        w2[4 * k] = v.x; w2[4 * k + 1] = v.y;
        w2[4 * k + 2] = v.z; w2[4 * k + 3] = v.w;
    }
    const float qb = qs[lane] + b2[lane];
    const float vr = Vw[lane];
    const float vb = Vb[0];
    const int tbase = blockIdx.x * (4 * TW) + wv * TW;
    const float* yd = y + (size_t)d * TT * HH;

    for (int i = 0; i < TW; i++) {
        const int t = tbase + i;
        const float* yrow = yd + (size_t)t * HH;
        float a0 = 0.f, a1 = 0.f, a2 = 0.f, a3 = 0.f;
#pragma unroll
        for (int k = 0; k < 64; k += 4) {
            float4 yv = *(const float4*)&yrow[k];
            a0 = fmaf(yv.x, w2[k], a0);
            a1 = fmaf(yv.y, w2[k + 1], a1);
            a2 = fmaf(yv.z, w2[k + 2], a2);
            a3 = fmaf(yv.w, w2[k + 3], a3);
        }
        float v = fast_tanh(qb + (a0 + a1) + (a2 + a3));
        float s = v * vr;
#pragma unroll
        for (int off = 32; off > 0; off >>= 1) s += __shfl_xor(s, off);
        if (lane == 0) score[(size_t)d * TT + t] = s + vb;
    }
}

// ---------------------------------------------------------------------------
// Kernel 4: per-day softmax over T + ctx[d][j] = sum_t attn * y
// ---------------------------------------------------------------------------
__global__ __launch_bounds__(256) void ctx_kernel(
    const float* __restrict__ score, const float* __restrict__ y,
    float* __restrict__ ctx)
{
    const int d = blockIdx.x;
    const int tid = threadIdx.x;
    __shared__ float red[256];
    const float* sc = score + (size_t)d * TT;

    float m = -1e30f;
    for (int t = tid; t < TT; t += 256) m = fmaxf(m, sc[t]);
    red[tid] = m; __syncthreads();
    for (int s = 128; s > 0; s >>= 1) {
        if (tid < s) red[tid] = fmaxf(red[tid], red[tid + s]);
        __syncthreads();
    }
    m = red[0]; __syncthreads();

    float se = 0.f;
    for (int t = tid; t < TT; t += 256) se += __expf(sc[t] - m);
    red[tid] = se; __syncthreads();
    for (int s = 128; s > 0; s >>= 1) {
        if (tid < s) red[tid] += red[tid + s];
        __syncthreads();
    }
    const float inv = 1.f / red[0];
    __syncthreads();

    const int j = tid & 63, grp = tid >> 6;
    const float* yd = y + (size_t)d * TT * HH;
    float a = 0.f;
    for (int t = grp; t < TT; t += 4)
        a = fmaf(__expf(sc[t] - m), yd[(size_t)t * HH + j], a);
    red[tid] = a; __syncthreads();
    if (tid < 64)
        ctx[d * 64 + tid] =
            (red[tid] + red[tid + 64] + red[tid + 128] + red[tid + 192]) * inv;
}

// ---------------------------------------------------------------------------
// Kernel 5: day LSTM (1 step) + day attention + stock head -> out[1]
// ---------------------------------------------------------------------------
__global__ __launch_bounds__(320) void final_kernel(
    const float* __restrict__ ctx,
    const float* __restrict__ Wih, const float* __restrict__ bih,
    const float* __restrict__ bhh,
    const float* __restrict__ W1, const float* __restrict__ b1,
    const float* __restrict__ W2, const float* __restrict__ b2,
    const float* __restrict__ Vw, const float* __restrict__ Vb,
    const float* __restrict__ stw, const float* __restrict__ stb,
    float* __restrict__ out)
{
    const int tid = threadIdx.x;
    const int dd = tid >> 6, j = tid & 63;
    __shared__ __align__(16) float ctxs[320];
    __shared__ float gsh[5 * 256];
    __shared__ __align__(16) float fulls[320];
    __shared__ __align__(16) float lasts[320];
    __shared__ float s2[5];

    ctxs[tid] = ctx[tid];
    __syncthreads();

    if (tid < 256) {
        float w[64];
#pragma unroll
        for (int k = 0; k < 16; k++) {
            float4 v = *(const float4*)&Wih[tid * 64 + 4 * k];
            w[4 * k] = v.x; w[4 * k + 1] = v.y;
            w[4 * k + 2] = v.z; w[4 * k + 3] = v.w;
        }
        const float bb = bih[tid] + bhh[tid];
        for (int dday = 0; dday < 5; ++dday) {
            float acc = bb;
#pragma unroll
            for (int k = 0; k < 64; k += 4) {
                float4 c4 = *(const float4*)&ctxs[dday * 64 + k];
                acc += w[k] * c4.x + w[k + 1] * c4.y + w[k + 2] * c4.z +
                       w[k + 3] * c4.w;
            }
            gsh[dday * 256 + tid] = acc;
        }
    }
    __syncthreads();
    {
        float gi = gsh[dd * 256 + j];
        float gg2 = gsh[dd * 256 + 128 + j];
        float go = gsh[dd * 256 + 192 + j];
        float c = fast_sig(gi) * fast_tanh(gg2);
        float hd = fast_sig(go) * fast_tanh(c);
        lasts[tid] = hd;
        fulls[tid] = fast_tanh(hd);
    }
    __syncthreads();
    {
        float w1r[64], w2r[64];
#pragma unroll
        for (int k = 0; k < 16; k++) {
            float4 v1 = *(const float4*)&W1[j * 64 + 4 * k];
            float4 v2 = *(const float4*)&W2[j * 64 + 4 * k];
            w1r[4 * k] = v1.x; w1r[4 * k + 1] = v1.y;
            w1r[4 * k + 2] = v1.z; w1r[4 * k + 3] = v1.w;
            w2r[4 * k] = v2.x; w2r[4 * k + 1] = v2.y;
            w2r[4 * k + 2] = v2.z; w2r[4 * k + 3] = v2.w;
        }
        float acc = b1[j] + b2[j];
#pragma unroll
        for (int k = 0; k < 64; ++k)
            acc += w1r[k] * lasts[dd * 64 + k] + w2r[k] * fulls[dd * 64 + k];
        float v = fast_tanh(acc) * Vw[j];
#pragma unroll
        for (int off = 32; off > 0; off >>= 1) v += __shfl_xor(v, off);
        if (j == 0) s2[dd] = v + Vb[0];
    }
    __syncthreads();
    if (tid < 64) {
        float m = s2[0];
#pragma unroll
        for (int dday = 1; dday < 5; ++dday) m = fmaxf(m, s2[dday]);
        float se = 0.f, ft = 0.f;
#pragma unroll
        for (int dday = 0; dday < 5; ++dday) {
            float e = __expf(s2[dday] - m);
            se += e;
            ft += e * fulls[dday * 64 + tid];
        }
        ft /= se;
        float pv = ft * stw[tid];
#pragma unroll
        for (int off = 32; off > 0; off >>= 1) pv += __shfl_xor(pv, off);
        if (tid == 0) out[0] = 3.f * fast_tanh(pv + stb[0]);
    }
}

// ---------------------------------------------------------------------------
extern "C" void kernel_launch(void* const* d_in, const int* in_sizes, int n_in,
                              void* d_out, int out_size, void* d_ws,
                              size_t ws_size, hipStream_t stream)
{
    const float* x     = (const float*)d_in[0];
    const float* ts    = (const float*)d_in[1];
    const float* Wallw = (const float*)d_in[3];
    const float* Wallb = (const float*)d_in[4];
    const float* Uallw = (const float*)d_in[5];
    const float* Uallb = (const float*)d_in[6];
    const float* Wdw   = (const float*)d_in[7];
    const float* Wdb   = (const float*)d_in[8];
    const float* taW1w = (const float*)d_in[9];
    const float* taW1b = (const float*)d_in[10];
    const float* taW2w = (const float*)d_in[11];
    const float* taW2b = (const float*)d_in[12];
    const float* taVw  = (const float*)d_in[13];
    const float* taVb  = (const float*)d_in[14];
    const float* Wih   = (const float*)d_in[15];
    const float* bih   = (const float*)d_in[17];
    const float* bhh   = (const float*)d_in[18];
    const float* daW1w = (const float*)d_in[19];
    const float* daW1b = (const float*)d_in[20];
    const float* daW2w = (const float*)d_in[21];
    const float* daW2b = (const float*)d_in[22];
    const float* daVw  = (const float*)d_in[23];
    const float* daVb  = (const float*)d_in[24];
    const float* stw   = (const float*)d_in[25];
    const float* stb   = (const float*)d_in[26];
    float* out = (float*)d_out;

    float* ux = (float*)d_ws;                       // [5][8192][256]
    float* yb = ux + (size_t)DDAYS * TT * GG;       // [5][8192][64]
    float* sc = yb + (size_t)DDAYS * TT * HH;       // [5][8192]
    float* hf = sc + (size_t)DDAYS * TT;            // [5][64]
    float* cx = hf + 512;                           // [5][64]

    gemm_ux<<<dim3(320, 2), 256, 0, stream>>>(x, Uallw, ux);
    scan_kernel<<<dim3(DDAYS), 256, 0, stream>>>(ux, ts, Wallw, Wallb, Uallb,
                                                 Wdw, Wdb, yb, hf);
    score_kernel<<<dim3(TT / (4 * TW), DDAYS), 256, 0, stream>>>(
        yb, hf, taW1w, taW1b, taW2w, taW2b, taVw, taVb, sc);
    ctx_kernel<<<dim3(DDAYS), 256, 0, stream>>>(sc, yb, cx);
    final_kernel<<<dim3(1), 320, 0, stream>>>(cx, Wih, bih, bhh, daW1w, daW1b,
                                              daW2w, daW2b, daVw, daVb, stw,
                                              stb, out);
}

// Round 5
// 5510.291 us; speedup vs baseline: 1.2787x; 1.2384x over previous
//
#include <hip/hip_runtime.h>
#include <hip/hip_bf16.h>
#include <cstdint>

#define DDAYS 5
#define TT 8192
#define FF 768
#define HH 64
#define GG 256  // 4*H

typedef _Float16 h2f __attribute__((ext_vector_type(2)));

#if __has_builtin(__builtin_amdgcn_fdot2)
#define FDOT2(a, b, c) __builtin_amdgcn_fdot2((a), (b), (c), false)
#else
#define FDOT2(a, b, c) fmaf((float)(a).x, (float)(b).x, fmaf((float)(a).y, (float)(b).y, (c)))
#endif

__device__ __forceinline__ float fast_tanh(float x) {
    return 1.f - 2.f / (__expf(2.f * x) + 1.f);
}
__device__ __forceinline__ float fast_sig(float x) {
    return 1.f / (1.f + __expf(-x));
}

// ---------------------------------------------------------------------------
// Kernel 1: ux[m][g] = sum_f A[m][f] * B[g][f]   (bias added later in scan)
// ---------------------------------------------------------------------------
__global__ __launch_bounds__(256, 2) void gemm_ux(
    const float* __restrict__ A, const float* __restrict__ B,
    float* __restrict__ C)
{
    __shared__ __align__(16) float As[16][132];
    __shared__ __align__(16) float Bs[16][132];
    const int tid = threadIdx.x;
    const int m0 = blockIdx.x * 128;
    const int n0 = blockIdx.y * 128;
    const int tx = tid & 15, ty = tid >> 4;
    const int i0 = tx * 8, j0 = ty * 8;
    const int lrow = tid >> 2, lc4 = tid & 3;

    const float* Ap = A + (size_t)(m0 + lrow) * FF + lc4 * 4;
    const float* Bp = B + (size_t)(n0 + lrow) * FF + lc4 * 4;

    float4 pa0 = *(const float4*)(Ap);
    float4 pa1 = *(const float4*)(Ap + 64 * FF);
    float4 pb0 = *(const float4*)(Bp);
    float4 pb1 = *(const float4*)(Bp + 64 * FF);

    float acc[8][8] = {};

    for (int kt = 0; kt < FF / 16; ++kt) {
        __syncthreads();
        {
            const int kk = lc4 * 4;
            As[kk + 0][lrow] = pa0.x; As[kk + 1][lrow] = pa0.y;
            As[kk + 2][lrow] = pa0.z; As[kk + 3][lrow] = pa0.w;
            As[kk + 0][lrow + 64] = pa1.x; As[kk + 1][lrow + 64] = pa1.y;
            As[kk + 2][lrow + 64] = pa1.z; As[kk + 3][lrow + 64] = pa1.w;
            Bs[kk + 0][lrow] = pb0.x; Bs[kk + 1][lrow] = pb0.y;
            Bs[kk + 2][lrow] = pb0.z; Bs[kk + 3][lrow] = pb0.w;
            Bs[kk + 0][lrow + 64] = pb1.x; Bs[kk + 1][lrow + 64] = pb1.y;
            Bs[kk + 2][lrow + 64] = pb1.z; Bs[kk + 3][lrow + 64] = pb1.w;
        }
        __syncthreads();
        if (kt + 1 < FF / 16) {
            const int k0 = (kt + 1) * 16;
            pa0 = *(const float4*)(Ap + k0);
            pa1 = *(const float4*)(Ap + 64 * FF + k0);
            pb0 = *(const float4*)(Bp + k0);
            pb1 = *(const float4*)(Bp + 64 * FF + k0);
        }
#pragma unroll
        for (int k = 0; k < 16; ++k) {
            float a[8], b[8];
            *(float4*)&a[0] = *(const float4*)&As[k][i0];
            *(float4*)&a[4] = *(const float4*)&As[k][i0 + 4];
            *(float4*)&b[0] = *(const float4*)&Bs[k][j0];
            *(float4*)&b[4] = *(const float4*)&Bs[k][j0 + 4];
#pragma unroll
            for (int r = 0; r < 8; ++r)
#pragma unroll
                for (int c = 0; c < 8; ++c)
                    acc[r][c] = fmaf(a[r], b[c], acc[r][c]);
        }
    }
#pragma unroll
    for (int r = 0; r < 8; ++r) {
        float4 s0 = make_float4(acc[r][0], acc[r][1], acc[r][2], acc[r][3]);
        float4 s1 = make_float4(acc[r][4], acc[r][5], acc[r][6], acc[r][7]);
        float* Cp = C + (size_t)(m0 + i0 + r) * GG + n0 + j0;
        *(float4*)Cp = s0;
        *(float4*)(Cp + 4) = s1;
    }
}

// ---------------------------------------------------------------------------
// Kernel 2: TimeLSTM scan. One block (2 waves = 128 thr) per day.
// R5 redesign: the R1-R4 structures were LDS-PIPE bound (~116 DS ops/CU/step
// ≈ 1300 cyc at b128~12cyc). Now: lane = (g0=lane>>5, jl=lane&31); wave wv
// owns columns jj = 32wv+jl; each lane computes TWO gate rows:
//   g0=0: f=jj, o=128+jj ; g0=1: i=64+jj, g=192+jj
// Gate exchange + c-dot reduce = 3x shfl_xor(32) (intra-wave). h,c stored
// as f16 in LDS (h: 8x b128, c-half: 4x b128 per wave). True c accumulator
// stays f32 in registers (both partner lanes keep identical copies).
// Dots via v_dot2_f32_f16. One raw lgkmcnt-only barrier per step.
// ---------------------------------------------------------------------------
__global__ __launch_bounds__(128, 1) void scan_kernel(
    const float* __restrict__ ux, const float* __restrict__ ts,
    const float* __restrict__ Ww, const float* __restrict__ Wb,
    const float* __restrict__ Ub,
    const float* __restrict__ Dw, const float* __restrict__ Db,
    float* __restrict__ y, float* __restrict__ hfin)
{
    const int d = blockIdx.x;
    const int tid = threadIdx.x;
    const int wv = tid >> 6;
    const int l  = tid & 63;
    const int jl = l & 31;
    const int g0 = l >> 5;
    const int jj = (wv << 5) | jl;        // column 0..63
    const int rA = (g0 << 6) + jj;        // f (g0=0) / i (g0=1)
    const int rB = 128 + (g0 << 6) + jj;  // o (g0=0) / g (g0=1)

    // one-time: convert this lane's weight rows to f16 pairs (registers)
    h2f wAr[32], wBr[32], wdr[16];
    {
        const float2* pA = (const float2*)(Ww + (size_t)rA * 64);
        const float2* pB = (const float2*)(Ww + (size_t)rB * 64);
#pragma unroll
        for (int k = 0; k < 32; ++k) {
            float2 a = pA[k], b = pB[k];
            wAr[k] = h2f{(_Float16)a.x, (_Float16)a.y};
            wBr[k] = h2f{(_Float16)b.x, (_Float16)b.y};
        }
        const float2* pD = (const float2*)(Dw + (size_t)jj * 64 + (g0 << 5));
#pragma unroll
        for (int k = 0; k < 16; ++k) {
            float2 v = pD[k];
            wdr[k] = h2f{(_Float16)v.x, (_Float16)v.y};
        }
    }
    const float biasA = Wb[rA] + Ub[rA];
    const float biasB = Wb[rB] + Ub[rB];
    const float wdb = Db[jj];
    // gB activation: sigmoid for o (g0=0), tanh for g (g0=1): tanh(x)=2*sig(2x)-1
    const float bmul = g0 ? 2.f : 1.f;
    const float bsub = g0 ? 1.f : 0.f;

    __shared__ __align__(16) _Float16 h_lds[2][64];
    __shared__ __align__(16) _Float16 c_lds[2][64];
    if (tid < 64) {
        h_lds[0][tid] = (_Float16)0.f;
        c_lds[0][tid] = (_Float16)0.f;
    }
    __syncthreads();

    const float* uxd  = ux + (size_t)d * TT * GG;
    const float* uA_p = uxd + rA;
    const float* uB_p = uxd + rB;
    const float* tsd  = ts + (size_t)d * TT;
    float* yd = y + (size_t)d * TT * HH;

    float uA[4], uB[4], tp[4];
#pragma unroll
    for (int i = 0; i < 4; ++i) {
        uA[i] = uA_p[(size_t)i * GG];
        uB[i] = uB_p[(size_t)i * GG];
        tp[i] = tsd[i];
    }

    float c_old = 0.f;

    for (int t = 0; t < TT; t += 4) {
#pragma unroll
        for (int i = 0; i < 4; ++i) {
            const int tc = t + i;
            const int rb = tc & 1, nb = rb ^ 1;
            const float ucA = uA[i], ucB = uB[i], tcur = tp[i];
            {   // prefetch step tc+4 (stays in flight across the raw barrier)
                int tn = tc + 4; if (tn > TT - 1) tn = TT - 1;
                uA[i] = uA_p[(size_t)tn * GG];
                uB[i] = uB_p[(size_t)tn * GG];
                tp[i] = tsd[tn];
            }

            // h: 64 f16 = 8x ds_read_b128 (broadcast)
            h2f hp[32];
            {
                const uint4* hb = (const uint4*)&h_lds[rb][0];
#pragma unroll
                for (int k = 0; k < 8; ++k) {
                    uint4 v = hb[k];
                    hp[4 * k + 0] = __builtin_bit_cast(h2f, v.x);
                    hp[4 * k + 1] = __builtin_bit_cast(h2f, v.y);
                    hp[4 * k + 2] = __builtin_bit_cast(h2f, v.z);
                    hp[4 * k + 3] = __builtin_bit_cast(h2f, v.w);
                }
            }
            // c half (this lane's k-range): 32 f16 = 4x ds_read_b128
            h2f cp[16];
            {
                const uint4* cb = (const uint4*)(&c_lds[rb][0] + (g0 << 5));
#pragma unroll
                for (int k = 0; k < 4; ++k) {
                    uint4 v = cb[k];
                    cp[4 * k + 0] = __builtin_bit_cast(h2f, v.x);
                    cp[4 * k + 1] = __builtin_bit_cast(h2f, v.y);
                    cp[4 * k + 2] = __builtin_bit_cast(h2f, v.z);
                    cp[4 * k + 3] = __builtin_bit_cast(h2f, v.w);
                }
            }

            // two row-dots over h (shared hp operands)
            float a0 = 0.f, a1 = 0.f, a2 = 0.f, a3 = 0.f;
            float b0 = 0.f, b1 = 0.f, b2 = 0.f, b3 = 0.f;
#pragma unroll
            for (int k = 0; k < 32; k += 4) {
                a0 = FDOT2(wAr[k + 0], hp[k + 0], a0);
                a1 = FDOT2(wAr[k + 1], hp[k + 1], a1);
                a2 = FDOT2(wAr[k + 2], hp[k + 2], a2);
                a3 = FDOT2(wAr[k + 3], hp[k + 3], a3);
                b0 = FDOT2(wBr[k + 0], hp[k + 0], b0);
                b1 = FDOT2(wBr[k + 1], hp[k + 1], b1);
                b2 = FDOT2(wBr[k + 2], hp[k + 2], b2);
                b3 = FDOT2(wBr[k + 3], hp[k + 3], b3);
            }
            // half-dot of W_d row jj over c
            float p0 = 0.f, p1 = 0.f;
#pragma unroll
            for (int k = 0; k < 16; k += 2) {
                p0 = FDOT2(wdr[k + 0], cp[k + 0], p0);
                p1 = FDOT2(wdr[k + 1], cp[k + 1], p1);
            }
            float p = p0 + p1;
            p += __shfl_xor(p, 32);
            const float cs1 = fast_tanh(p + wdb);

            const float preA = (a0 + a1) + (a2 + a3) + biasA + ucA;
            const float preB = (b0 + b1) + (b2 + b3) + biasB + ucB;
            const float gA = fast_sig(preA);                 // f or i
            const float q  = fast_sig(preB * bmul);
            const float gB = fmaf(q, bmul, -bsub);           // o (sig) or g (tanh)

            const float gA2 = __shfl_xor(gA, 32);
            const float gB2 = __shfl_xor(gB, 32);
            const float f  = g0 ? gA2 : gA;
            const float ii = g0 ? gA  : gA2;
            const float oo = g0 ? gB2 : gB;
            const float gg = g0 ? gB  : gB2;

            const float cadj = fmaf(cs1, tcur - 1.f, c_old);
            const float cn = fmaf(f, cadj, ii * gg);
            const float hn = oo * fast_tanh(cn);
            c_old = cn;

            if (g0 == 0) {
                h_lds[nb][jj] = (_Float16)hn;
                yd[(size_t)tc * HH + jj] = fast_tanh(gB);    // y = tanh(sig(o_pre))
            } else {
                c_lds[nb][jj] = (_Float16)cn;
            }

            // raw barrier: LDS-visibility only; global prefetches stay in flight
            asm volatile("s_waitcnt lgkmcnt(0)" ::: "memory");
            __builtin_amdgcn_sched_barrier(0);
            __builtin_amdgcn_s_barrier();
            __builtin_amdgcn_sched_barrier(0);
        }
    }
    // final state: step TT-1 wrote buffer 0 (TT even). f16-rounded h_fin is
    // well within tolerance (5e-4 rel).
    if (tid < 64) hfin[d * 64 + tid] = (float)h_lds[0][tid];
}

// ---------------------------------------------------------------------------
// Kernel 3: score[d][t] = V . tanh(q_d + W2 y_dt + b2) + Vb
// ---------------------------------------------------------------------------
#define TW 32
__global__ __launch_bounds__(256) void score_kernel(
    const float* __restrict__ y, const float* __restrict__ hfin,
    const float* __restrict__ W1, const float* __restrict__ b1,
    const float* __restrict__ W2, const float* __restrict__ b2,
    const float* __restrict__ Vw, const float* __restrict__ Vb,
    float* __restrict__ score)
{
    const int d = blockIdx.y;
    const int tid = threadIdx.x;
    const int lane = tid & 63, wv = tid >> 6;
    __shared__ __align__(16) float hf[64];
    __shared__ float qs[64];
    if (tid < 64) hf[tid] = hfin[d * 64 + tid];
    __syncthreads();
    if (tid < 64) {
        float acc = b1[tid];
#pragma unroll
        for (int k = 0; k < 16; k++) {
            float4 w = *(const float4*)&W1[tid * 64 + 4 * k];
            float4 h4 = *(const float4*)&hf[4 * k];
            acc += w.x * h4.x + w.y * h4.y + w.z * h4.z + w.w * h4.w;
        }
        qs[tid] = acc;
    }
    __syncthreads();

    float w2[64];
#pragma unroll
    for (int k = 0; k < 16; k++) {
        float4 v = *(const float4*)&W2[lane * 64 + 4 * k];
        w2[4 * k] = v.x; w2[4 * k + 1] = v.y;
        w2[4 * k + 2] = v.z; w2[4 * k + 3] = v.w;
    }
    const float qb = qs[lane] + b2[lane];
    const float vr = Vw[lane];
    const float vb = Vb[0];
    const int tbase = blockIdx.x * (4 * TW) + wv * TW;
    const float* yd = y + (size_t)d * TT * HH;

    for (int i = 0; i < TW; i++) {
        const int t = tbase + i;
        const float* yrow = yd + (size_t)t * HH;
        float a0 = 0.f, a1 = 0.f, a2 = 0.f, a3 = 0.f;
#pragma unroll
        for (int k = 0; k < 64; k += 4) {
            float4 yv = *(const float4*)&yrow[k];
            a0 = fmaf(yv.x, w2[k], a0);
            a1 = fmaf(yv.y, w2[k + 1], a1);
            a2 = fmaf(yv.z, w2[k + 2], a2);
            a3 = fmaf(yv.w, w2[k + 3], a3);
        }
        float v = fast_tanh(qb + (a0 + a1) + (a2 + a3));
        float s = v * vr;
#pragma unroll
        for (int off = 32; off > 0; off >>= 1) s += __shfl_xor(s, off);
        if (lane == 0) score[(size_t)d * TT + t] = s + vb;
    }
}

// ---------------------------------------------------------------------------
// Kernel 4: per-day softmax over T + ctx[d][j] = sum_t attn * y
// ---------------------------------------------------------------------------
__global__ __launch_bounds__(256) void ctx_kernel(
    const float* __restrict__ score, const float* __restrict__ y,
    float* __restrict__ ctx)
{
    const int d = blockIdx.x;
    const int tid = threadIdx.x;
    __shared__ float red[256];
    const float* sc = score + (size_t)d * TT;

    float m = -1e30f;
    for (int t = tid; t < TT; t += 256) m = fmaxf(m, sc[t]);
    red[tid] = m; __syncthreads();
    for (int s = 128; s > 0; s >>= 1) {
        if (tid < s) red[tid] = fmaxf(red[tid], red[tid + s]);
        __syncthreads();
    }
    m = red[0]; __syncthreads();

    float se = 0.f;
    for (int t = tid; t < TT; t += 256) se += __expf(sc[t] - m);
    red[tid] = se; __syncthreads();
    for (int s = 128; s > 0; s >>= 1) {
        if (tid < s) red[tid] += red[tid + s];
        __syncthreads();
    }
    const float inv = 1.f / red[0];
    __syncthreads();

    const int j = tid & 63, grp = tid >> 6;
    const float* yd = y + (size_t)d * TT * HH;
    float a = 0.f;
    for (int t = grp; t < TT; t += 4)
        a = fmaf(__expf(sc[t] - m), yd[(size_t)t * HH + j], a);
    red[tid] = a; __syncthreads();
    if (tid < 64)
        ctx[d * 64 + tid] =
            (red[tid] + red[tid + 64] + red[tid + 128] + red[tid + 192]) * inv;
}

// ---------------------------------------------------------------------------
// Kernel 5: day LSTM (1 step) + day attention + stock head -> out[1]
// ---------------------------------------------------------------------------
__global__ __launch_bounds__(320) void final_kernel(
    const float* __restrict__ ctx,
    const float* __restrict__ Wih, const float* __restrict__ bih,
    const float* __restrict__ bhh,
    const float* __restrict__ W1, const float* __restrict__ b1,
    const float* __restrict__ W2, const float* __restrict__ b2,
    const float* __restrict__ Vw, const float* __restrict__ Vb,
    const float* __restrict__ stw, const float* __restrict__ stb,
    float* __restrict__ out)
{
    const int tid = threadIdx.x;
    const int dd = tid >> 6, j = tid & 63;
    __shared__ __align__(16) float ctxs[320];
    __shared__ float gsh[5 * 256];
    __shared__ __align__(16) float fulls[320];
    __shared__ __align__(16) float lasts[320];
    __shared__ float s2[5];

    ctxs[tid] = ctx[tid];
    __syncthreads();

    if (tid < 256) {
        float w[64];
#pragma unroll
        for (int k = 0; k < 16; k++) {
            float4 v = *(const float4*)&Wih[tid * 64 + 4 * k];
            w[4 * k] = v.x; w[4 * k + 1] = v.y;
            w[4 * k + 2] = v.z; w[4 * k + 3] = v.w;
        }
        const float bb = bih[tid] + bhh[tid];
        for (int dday = 0; dday < 5; ++dday) {
            float acc = bb;
#pragma unroll
            for (int k = 0; k < 64; k += 4) {
                float4 c4 = *(const float4*)&ctxs[dday * 64 + k];
                acc += w[k] * c4.x + w[k + 1] * c4.y + w[k + 2] * c4.z +
                       w[k + 3] * c4.w;
            }
            gsh[dday * 256 + tid] = acc;
        }
    }
    __syncthreads();
    {
        float gi = gsh[dd * 256 + j];
        float gg2 = gsh[dd * 256 + 128 + j];
        float go = gsh[dd * 256 + 192 + j];
        float c = fast_sig(gi) * fast_tanh(gg2);
        float hd = fast_sig(go) * fast_tanh(c);
        lasts[tid] = hd;
        fulls[tid] = fast_tanh(hd);
    }
    __syncthreads();
    {
        float w1r[64], w2r[64];
#pragma unroll
        for (int k = 0; k < 16; k++) {
            float4 v1 = *(const float4*)&W1[j * 64 + 4 * k];
            float4 v2 = *(const float4*)&W2[j * 64 + 4 * k];
            w1r[4 * k] = v1.x; w1r[4 * k + 1] = v1.y;
            w1r[4 * k + 2] = v1.z; w1r[4 * k + 3] = v1.w;
            w2r[4 * k] = v2.x; w2r[4 * k + 1] = v2.y;
            w2r[4 * k + 2] = v2.z; w2r[4 * k + 3] = v2.w;
        }
        float acc = b1[j] + b2[j];
#pragma unroll
        for (int k = 0; k < 64; ++k)
            acc += w1r[k] * lasts[dd * 64 + k] + w2r[k] * fulls[dd * 64 + k];
        float v = fast_tanh(acc) * Vw[j];
#pragma unroll
        for (int off = 32; off > 0; off >>= 1) v += __shfl_xor(v, off);
        if (j == 0) s2[dd] = v + Vb[0];
    }
    __syncthreads();
    if (tid < 64) {
        float m = s2[0];
#pragma unroll
        for (int dday = 1; dday < 5; ++dday) m = fmaxf(m, s2[dday]);
        float se = 0.f, ft = 0.f;
#pragma unroll
        for (int dday = 0; dday < 5; ++dday) {
            float e = __expf(s2[dday] - m);
            se += e;
            ft += e * fulls[dday * 64 + tid];
        }
        ft /= se;
        float pv = ft * stw[tid];
#pragma unroll
        for (int off = 32; off > 0; off >>= 1) pv += __shfl_xor(pv, off);
        if (tid == 0) out[0] = 3.f * fast_tanh(pv + stb[0]);
    }
}

// ---------------------------------------------------------------------------
extern "C" void kernel_launch(void* const* d_in, const int* in_sizes, int n_in,
                              void* d_out, int out_size, void* d_ws,
                              size_t ws_size, hipStream_t stream)
{
    const float* x     = (const float*)d_in[0];
    const float* ts    = (const float*)d_in[1];
    const float* Wallw = (const float*)d_in[3];
    const float* Wallb = (const float*)d_in[4];
    const float* Uallw = (const float*)d_in[5];
    const float* Uallb = (const float*)d_in[6];
    const float* Wdw   = (const float*)d_in[7];
    const float* Wdb   = (const float*)d_in[8];
    const float* taW1w = (const float*)d_in[9];
    const float* taW1b = (const float*)d_in[10];
    const float* taW2w = (const float*)d_in[11];
    const float* taW2b = (const float*)d_in[12];
    const float* taVw  = (const float*)d_in[13];
    const float* taVb  = (const float*)d_in[14];
    const float* Wih   = (const float*)d_in[15];
    const float* bih   = (const float*)d_in[17];
    const float* bhh   = (const float*)d_in[18];
    const float* daW1w = (const float*)d_in[19];
    const float* daW1b = (const float*)d_in[20];
    const float* daW2w = (const float*)d_in[21];
    const float* daW2b = (const float*)d_in[22];
    const float* daVw  = (const float*)d_in[23];
    const float* daVb  = (const float*)d_in[24];
    const float* stw   = (const float*)d_in[25];
    const float* stb   = (const float*)d_in[26];
    float* out = (float*)d_out;

    float* ux = (float*)d_ws;                       // [5][8192][256]
    float* yb = ux + (size_t)DDAYS * TT * GG;       // [5][8192][64]
    float* sc = yb + (size_t)DDAYS * TT * HH;       // [5][8192]
    float* hf = sc + (size_t)DDAYS * TT;            // [5][64]
    float* cx = hf + 512;                           // [5][64]

    gemm_ux<<<dim3(320, 2), 256, 0, stream>>>(x, Uallw, ux);
    scan_kernel<<<dim3(DDAYS), 128, 0, stream>>>(ux, ts, Wallw, Wallb, Uallb,
                                                 Wdw, Wdb, yb, hf);
    score_kernel<<<dim3(TT / (4 * TW), DDAYS), 256, 0, stream>>>(
        yb, hf, taW1w, taW1b, taW2w, taW2b, taVw, taVb, sc);
    ctx_kernel<<<dim3(DDAYS), 256, 0, stream>>>(sc, yb, cx);
    final_kernel<<<dim3(1), 320, 0, stream>>>(cx, Wih, bih, bhh, daW1w, daW1b,
                                              daW2w, daW2b, daVw, daVb, stw,
                                              stb, out);
}